// Round 8
// baseline (266.216 us; speedup 1.0000x reference)
//
#include <hip/hip_runtime.h>
#include <hip/hip_bf16.h>

// GCN VGAE encoder, 5 dispatches:
//   memset ccur | k_bin (LDS counting-sort, 8192-edge chunks) |
//   k_fine_gemm1 (fine scan + srcidx emit + same-block gemm1) |
//   k_gatherB (gather-L1 SEQUENTIAL planes -> h in LDS -> gemm2 from LDS) |
//   k_gather<L2 -> out, XCD-parity planes>
// norm factorization: agg[c] = dinv[c]*(sum_e ts[src] + ts[c]) + b, ts = (X@W)*dinv.
// Notes: coop grid.sync ~75us each (R11); degree-sorted perm REGRESSED (R14);
// scattered per-node global atomics REGRESSED +50us (R15: ~30ns/atomic ping-pong).
// R16: ~26.5us per gather dispatch incl overhead; timeline algebra (R19) says
//   per-dispatch overhead ~10-12us -> 6 dispatches = ~65us of gap.
// R17: counting-sort k_bin + LDS-staged srcidx: 231.7->223.6 (srcidx stage = win).
// R18: gemm1 fused into k_fine: kernel 43us (13% occ), -1 dispatch; 223.2 = best.
// R19: k_bin CHUNK 8192 ~ 2048 (223.2/226.5); k_bin <43us, not the monster.
// R20: gatherA fused with PARALLEL dual-plane accumulation: 244 VGPR, 8% occ,
//      80us, FETCH 87MB -> REGRESSED +26. Register blow-up, not concept failure.
// R21 (this): same fusion, SEQUENTIAL planes (p-loop over verified 40-VGPR
//      gather_core), h in LDS, gemm2 from LDS. Target ~70 VGPR, 4 blocks/CU.

constexpr int SH = 7;            // nodes per coarse bucket = 128
constexpr int NB = 1 << SH;      // 128
constexpr int CAP = 6144;        // slab capacity (mean ~4093, ~32 sigma)
constexpr int BMAX = 512;        // max buckets (N <= 65536)
constexpr int CHUNK = 8192;      // edges per block in k_bin
constexpr int EPT = 16;          // register-cached edges/thread in k_fine

typedef float vf4 __attribute__((ext_vector_type(4)));   // for nontemporal stores

__device__ __forceinline__ void fma4(float4& a, float s, const float4& w) {
    a.x = fmaf(s, w.x, a.x);
    a.y = fmaf(s, w.y, a.y);
    a.z = fmaf(s, w.z, a.z);
    a.w = fmaf(s, w.w, a.w);
}

__device__ __forceinline__ unsigned short f2bf(float f) {  // RNE
    unsigned u = __float_as_uint(f);
    return (unsigned short)((u + 0x7fffu + ((u >> 16) & 1u)) >> 16);
}

__device__ __forceinline__ void acc_bf8(float* a, uint4 v) {
    a[0] += __uint_as_float(v.x << 16);
    a[1] += __uint_as_float(v.x & 0xffff0000u);
    a[2] += __uint_as_float(v.y << 16);
    a[3] += __uint_as_float(v.y & 0xffff0000u);
    a[4] += __uint_as_float(v.z << 16);
    a[5] += __uint_as_float(v.z & 0xffff0000u);
    a[6] += __uint_as_float(v.w << 16);
    a[7] += __uint_as_float(v.w & 0xffff0000u);
}

__device__ __forceinline__ void set_bf8(float* a, uint4 v) {
    a[0] = __uint_as_float(v.x << 16);
    a[1] = __uint_as_float(v.x & 0xffff0000u);
    a[2] = __uint_as_float(v.y << 16);
    a[3] = __uint_as_float(v.y & 0xffff0000u);
    a[4] = __uint_as_float(v.z << 16);
    a[5] = __uint_as_float(v.z & 0xffff0000u);
    a[6] = __uint_as_float(v.w << 16);
    a[7] = __uint_as_float(v.w & 0xffff0000u);
}

// Sum of one (node, quad) stripe of a 32-feat bf16 plane into a[8] (fp32),
// including the self loop. 8-edge unroll for MLP.
__device__ __forceinline__ void gather_core(const int2* __restrict__ range2,
                                            const unsigned short* __restrict__ srcidx,
                                            const uint4* __restrict__ Tp,
                                            int n, int q, float* a) {
    int2 rg = range2[n];
    int k = rg.x, end = rg.y;
    set_bf8(a, Tp[(size_t)n * 4 + q]);       // self loop
    for (; k < end && (k & 3); ++k)          // align to ushort4
        acc_bf8(a, Tp[(size_t)srcidx[k] * 4 + q]);
    for (; k + 8 <= end; k += 8) {
        ushort4 r0 = *reinterpret_cast<const ushort4*>(srcidx + k);
        ushort4 r1 = *reinterpret_cast<const ushort4*>(srcidx + k + 4);
        uint4 v0 = Tp[(size_t)r0.x * 4 + q];
        uint4 v1 = Tp[(size_t)r0.y * 4 + q];
        uint4 v2 = Tp[(size_t)r0.z * 4 + q];
        uint4 v3 = Tp[(size_t)r0.w * 4 + q];
        uint4 v4 = Tp[(size_t)r1.x * 4 + q];
        uint4 v5 = Tp[(size_t)r1.y * 4 + q];
        uint4 v6 = Tp[(size_t)r1.z * 4 + q];
        uint4 v7 = Tp[(size_t)r1.w * 4 + q];
        acc_bf8(a, v0); acc_bf8(a, v1); acc_bf8(a, v2); acc_bf8(a, v3);
        acc_bf8(a, v4); acc_bf8(a, v5); acc_bf8(a, v6); acc_bf8(a, v7);
    }
    if (k + 4 <= end) {
        ushort4 r0 = *reinterpret_cast<const ushort4*>(srcidx + k);
        uint4 v0 = Tp[(size_t)r0.x * 4 + q];
        uint4 v1 = Tp[(size_t)r0.y * 4 + q];
        uint4 v2 = Tp[(size_t)r0.z * 4 + q];
        uint4 v3 = Tp[(size_t)r0.w * 4 + q];
        acc_bf8(a, v0); acc_bf8(a, v1); acc_bf8(a, v2); acc_bf8(a, v3);
        k += 4;
    }
    for (; k < end; ++k)
        acc_bf8(a, Tp[(size_t)srcidx[k] * 4 + q]);
}

// ---------------- k_bin ----------------
// LDS counting-sort per 8192-edge chunk:
//   pass1 hist(col>>SH) -> 512-wide block scan -> ONE ccur atomic per (block,bucket)
//   -> pass2 scatter packed edges into LDS sorted order -> contiguous run writes.
__global__ __launch_bounds__(256) void k_bin(const int* __restrict__ row,
                                             const int* __restrict__ col,
                                             int* __restrict__ ccur,
                                             unsigned* __restrict__ binned,
                                             int E, int B) {
    __shared__ int h[BMAX];       // hist -> running local offset
    __shared__ int lbase[BMAX];   // local exclusive base of bucket run
    __shared__ int gbase[BMAX];   // global slab base claimed for this block's run
    __shared__ int segtot[8];
    __shared__ unsigned sorted[CHUNK];   // 32KB
    const int tid = threadIdx.x;
    const int e0 = blockIdx.x * CHUNK;
    const int ecnt = min(E - e0, CHUNK);
    for (int i = tid; i < B; i += 256) h[i] = 0;
    __syncthreads();
    // pass1: histogram on col only
    for (int i = tid; i < ecnt; i += 256)
        atomicAdd(&h[col[e0 + i] >> SH], 1);
    __syncthreads();
    // block-wide exclusive scan over B (<=512) counts: 8 wave-segments + fixup
    int a0 = (tid < B) ? h[tid] : 0;
    int a1 = (tid + 256 < B) ? h[tid + 256] : 0;
    const int lane = tid & 63, wv = tid >> 6;
    int s0 = a0, s1 = a1;
    #pragma unroll
    for (int off = 1; off < 64; off <<= 1) {
        int u0 = __shfl_up(s0, off, 64);
        int u1 = __shfl_up(s1, off, 64);
        if (lane >= off) { s0 += u0; s1 += u1; }
    }
    if (lane == 63) { segtot[wv] = s0; segtot[4 + wv] = s1; }
    __syncthreads();
    int p0 = 0, p1 = 0;
    for (int j = 0; j < wv; ++j) p0 += segtot[j];
    for (int j = 0; j < 4 + wv; ++j) p1 += segtot[j];
    const int ex0 = s0 + p0 - a0;          // exclusive prefix, lanes [0,256)
    const int ex1 = s1 + p1 - a1;          // exclusive prefix, lanes [256,512)
    if (tid < B) {
        lbase[tid] = ex0; h[tid] = ex0;
        gbase[tid] = a0 ? atomicAdd(&ccur[tid], a0) : 0;
    }
    if (tid + 256 < B) {
        lbase[tid + 256] = ex1; h[tid + 256] = ex1;
        gbase[tid + 256] = a1 ? atomicAdd(&ccur[tid + 256], a1) : 0;
    }
    __syncthreads();
    // pass2: scatter into LDS sorted-by-bucket order (col reread: L2-hot)
    for (int i = tid; i < ecnt; i += 256) {
        int c = col[e0 + i], r = row[e0 + i];
        int pos = atomicAdd(&h[c >> SH], 1);
        sorted[pos] = ((unsigned)c << 16) | (unsigned)r;
    }
    __syncthreads();
    // write out: consecutive i within a run -> consecutive global addresses
    for (int i = tid; i < ecnt; i += 256) {
        unsigned e = sorted[i];
        int b = e >> (16 + SH);
        int g = gbase[b] + (i - lbase[b]);
        if (g < CAP) binned[(size_t)b * CAP + g] = e;
    }
}

// ---------------- k_fine_gemm1 (fused) ----------------
// One block per 128-node bucket:
//   phase A: register-cache entries; fine histogram -> dinv (LDS + global) +
//            (start,end) ranges (two-wave scan); srcidx via 12KB LDS stage + burst.
//   phase B: gemm1 for THIS bucket's 128 nodes (dinv is block-local -> no
//            cross-block dependency). W1 (32KB) staged to LDS early so its latency
//            hides under phase A. T planes (bf16 [N][32] x2) = (X @ W1) * dinv.
__global__ __launch_bounds__(256) void k_fine_gemm1(
    const unsigned* __restrict__ binned, const int* __restrict__ ccur,
    unsigned short* __restrict__ srcidx, int2* __restrict__ range2,
    float* __restrict__ dinv,
    const float* __restrict__ X, const float* __restrict__ W1,
    unsigned short* __restrict__ Tlo, unsigned short* __restrict__ Thi, int N) {
    __shared__ int fine[NB];
    __shared__ float dl[NB];
    __shared__ int w0tot;
    __shared__ uint4 sshv[CAP / 8];               // 12KB ushort stage
    __shared__ float4 Wl[2048];                   // 32KB W1 tile
    unsigned short* ssh = (unsigned short*)sshv;
    const int b = blockIdx.x;
    const int n0 = b << SH;
    const int ebase = b * CAP;
    const int ecnt = min(ccur[b], CAP);
    const int tid = threadIdx.x;
    if (tid < NB) fine[tid] = 0;
    // ---- phase A: fine binning ----
    unsigned ebuf[EPT];
    #pragma unroll
    for (int j = 0; j < EPT; ++j) {
        int i = tid + j * 256;
        ebuf[j] = (i < ecnt) ? binned[ebase + i] : 0xFFFFFFFFu;
    }
    // stage W1 early: global loads issue now, ds_writes retire under phase A
    for (int i = tid; i < 2048; i += 256)
        Wl[i] = reinterpret_cast<const float4*>(W1)[i];
    __syncthreads();
    #pragma unroll
    for (int j = 0; j < EPT; ++j)
        if (ebuf[j] != 0xFFFFFFFFu) atomicAdd(&fine[(ebuf[j] >> 16) & (NB - 1)], 1);
    for (int i = EPT * 256 + tid; i < ecnt; i += 256)   // overflow tail
        atomicAdd(&fine[(binned[ebase + i] >> 16) & (NB - 1)], 1);
    __syncthreads();
    // exclusive scan over 128 counts: per-wave inclusive scan, wave1 += wave0 total
    int v = (tid < NB) ? fine[tid] : 0;
    int s = v;
    const int lane = tid & 63;
    #pragma unroll
    for (int off = 1; off < 64; off <<= 1) {
        int u = __shfl_up(s, off, 64);
        if (lane >= off) s += u;
    }
    if (tid == 63) w0tot = s;
    __syncthreads();
    if (tid >= 64 && tid < NB) s += w0tot;
    if (tid < NB) {
        int lb = s - v;                    // LOCAL exclusive base
        int n = n0 + tid;
        float d = rsqrtf((float)v + 1.0f);
        dl[tid] = d;
        if (n < N) {
            range2[n] = make_int2(ebase + lb, ebase + lb + v);
            dinv[n] = d;
        }
        fine[tid] = lb;                    // local running counter
    }
    __syncthreads();
    #pragma unroll
    for (int j = 0; j < EPT; ++j) {
        unsigned e = ebuf[j];
        if (e != 0xFFFFFFFFu) {
            int pos = atomicAdd(&fine[(e >> 16) & (NB - 1)], 1);
            ssh[pos] = (unsigned short)(e & 0xFFFFu);
        }
    }
    for (int i = EPT * 256 + tid; i < ecnt; i += 256) {
        unsigned e = binned[ebase + i];
        int pos = atomicAdd(&fine[(e >> 16) & (NB - 1)], 1);
        ssh[pos] = (unsigned short)(e & 0xFFFFu);
    }
    __syncthreads();
    // coalesced srcidx copy-out (round up to 16B; slack stays inside this slab)
    const int n4 = ((ecnt + 7) & ~7) >> 3;
    uint4* gs = reinterpret_cast<uint4*>(srcidx + ebase);
    for (int j = tid; j < n4; j += 256) gs[j] = sshv[j];

    // ---- phase B: gemm1 for nodes [n0, n0+128) ----
    const int fg = tid & 15;           // 16 feature groups x float4 = 64 outputs
    const int ns = tid >> 4;           // 16 node slots, 8 nodes/thread
    const float4* Xv = reinterpret_cast<const float4*>(X);
    const float4 z = make_float4(0.f, 0.f, 0.f, 0.f);
    float4 acc[8] = {z, z, z, z, z, z, z, z};
    int n[8];
    bool vld[8];
    #pragma unroll
    for (int i = 0; i < 8; ++i) { n[i] = n0 + ns + i * 16; vld[i] = n[i] < N; }
    for (int k4 = 0; k4 < 32; ++k4) {
        float4 xv[8];
        #pragma unroll
        for (int i = 0; i < 8; ++i)
            xv[i] = vld[i] ? Xv[(size_t)n[i] * 32 + k4] : z;
        float4 w0 = Wl[(k4 * 4 + 0) * 16 + fg];
        float4 w1 = Wl[(k4 * 4 + 1) * 16 + fg];
        float4 w2 = Wl[(k4 * 4 + 2) * 16 + fg];
        float4 w3 = Wl[(k4 * 4 + 3) * 16 + fg];
        #pragma unroll
        for (int i = 0; i < 8; ++i) {
            fma4(acc[i], xv[i].x, w0); fma4(acc[i], xv[i].y, w1);
            fma4(acc[i], xv[i].z, w2); fma4(acc[i], xv[i].w, w3);
        }
    }
    ushort4* Tp = reinterpret_cast<ushort4*>((fg < 8) ? Tlo : Thi);
    const int j = fg & 7;
    #pragma unroll
    for (int i = 0; i < 8; ++i) {
        if (vld[i]) {
            float d = dl[ns + i * 16];
            ushort4 o;
            o.x = f2bf(acc[i].x * d); o.y = f2bf(acc[i].y * d);
            o.z = f2bf(acc[i].z * d); o.w = f2bf(acc[i].w * d);
            Tp[(size_t)n[i] * 8 + j] = o;
        }
    }
}

// ---------------- k_gatherB (fused gather-L1 + gemm2, SEQUENTIAL planes) ----------
// One block = 64 full nodes. Per thread (nl=tid>>2, q=tid&3): p-loop over the two
// T1 planes, each pass = verified gather_core (8 fp32 acc, ~40 VGPR), then
// h = relu(agg*dinv + b1) -> LDS hrow[64][68]. Then k_gemm<64> inner loop from LDS
// with W-pair (Wmu|Wls) in 16KB LDS -> T2 planes. The p-loop's loop-carried
// structure stops the compiler interleaving the two plane load streams (R20's
// 244-VGPR failure mode).
__global__ __launch_bounds__(256) void k_gatherB(
    const int2* __restrict__ range2, const unsigned short* __restrict__ srcidx,
    const uint4* __restrict__ Tlo, const uint4* __restrict__ Thi,
    const float* __restrict__ dinv, const float* __restrict__ b1,
    const float* __restrict__ Wmu, const float* __restrict__ Wls,
    unsigned short* __restrict__ T2lo, unsigned short* __restrict__ T2hi, int N) {
    __shared__ float4 Wl[1024];          // 16KB: [k][fg] fg<8->Wmu, fg>=8->Wls
    __shared__ float hrow[64][68];       // 17KB, padded rows
    const int tid = threadIdx.x;
    // stage W-pair early (latency hides under the gather loop)
    for (int i = tid; i < 1024; i += 256) {
        int k = i >> 4, fgi = i & 15;
        const float* sp = (fgi < 8) ? (Wmu + k * 32 + fgi * 4)
                                    : (Wls + k * 32 + (fgi - 8) * 4);
        Wl[i] = *reinterpret_cast<const float4*>(sp);
    }
    const int nl = tid >> 2, q = tid & 3;
    const int n = blockIdx.x * 64 + nl;
    const bool nv = n < N;
    const float d = nv ? dinv[n] : 0.f;
    for (int p = 0; p < 2; ++p) {
        if (nv) {
            float a[8];
            gather_core(range2, srcidx, p ? Thi : Tlo, n, q, a);
            const float* bb = b1 + p * 32 + q * 8;
            float* hr = &hrow[nl][p * 32 + q * 8];
            #pragma unroll
            for (int j = 0; j < 8; ++j)
                hr[j] = fmaxf(fmaf(a[j], d, bb[j]), 0.f);
        }
    }
    __syncthreads();
    // ---- gemm2 phase (k_gemm<64,...> inner loop, X from LDS) ----
    const int fg = tid & 15;
    const int ns = tid >> 4;
    const int nb = blockIdx.x * 64;
    const float4 z = make_float4(0.f, 0.f, 0.f, 0.f);
    float4 acc[4] = {z, z, z, z};
    for (int k4 = 0; k4 < 16; ++k4) {
        float4 w0 = Wl[(k4 * 4 + 0) * 16 + fg];
        float4 w1 = Wl[(k4 * 4 + 1) * 16 + fg];
        float4 w2 = Wl[(k4 * 4 + 2) * 16 + fg];
        float4 w3 = Wl[(k4 * 4 + 3) * 16 + fg];
        #pragma unroll
        for (int i = 0; i < 4; ++i) {
            float4 xv = *reinterpret_cast<const float4*>(&hrow[ns + i * 16][k4 * 4]);
            fma4(acc[i], xv.x, w0); fma4(acc[i], xv.y, w1);
            fma4(acc[i], xv.z, w2); fma4(acc[i], xv.w, w3);
        }
    }
    ushort4* Tp = reinterpret_cast<ushort4*>((fg < 8) ? T2lo : T2hi);
    const int j = fg & 7;
    #pragma unroll
    for (int i = 0; i < 4; ++i) {
        int ni = nb + ns + i * 16;
        if (ni < N) {
            float d2 = dinv[ni];
            ushort4 o;
            o.x = f2bf(acc[i].x * d2); o.y = f2bf(acc[i].y * d2);
            o.z = f2bf(acc[i].z * d2); o.w = f2bf(acc[i].w * d2);
            Tp[(size_t)ni * 8 + j] = o;
        }
    }
}

// ---------------- k_gather ----------------
// Both planes of one layer in a single dispatch, plane pinned by XCD parity:
// plane = blockIdx&1 (round-robin block->XCD mapping keeps each XCD on one 3.2MB
// plane -> per-XCD L2-resident). Grid = 2 * ceil(N*4/256).
template <bool NT>
__global__ __launch_bounds__(256) void k_gather(
    const int2* __restrict__ range2, const unsigned short* __restrict__ srcidx,
    const uint4* __restrict__ Tlo, const uint4* __restrict__ Thi,
    const float* __restrict__ dinv,
    const float* __restrict__ bias_lo, const float* __restrict__ bias_hi,
    float* __restrict__ dst_lo, float* __restrict__ dst_hi, int N) {
    const int plane = blockIdx.x & 1;
    int idx = (blockIdx.x >> 1) * 256 + threadIdx.x;
    if (idx >= N * 4) return;
    int n = idx >> 2, q = idx & 3;
    float a[8];
    gather_core(range2, srcidx, plane ? Thi : Tlo, n, q, a);
    float d = dinv[n];
    const float* bias = (plane ? bias_hi : bias_lo) + q * 8;
    float* dst = (plane ? dst_hi : dst_lo) + (size_t)n * 32 + q * 8;
    float4 b0 = reinterpret_cast<const float4*>(bias)[0];
    float4 b1 = reinterpret_cast<const float4*>(bias)[1];
    vf4 o0, o1;
    o0.x = fmaf(a[0], d, b0.x); o0.y = fmaf(a[1], d, b0.y);
    o0.z = fmaf(a[2], d, b0.z); o0.w = fmaf(a[3], d, b0.w);
    o1.x = fmaf(a[4], d, b1.x); o1.y = fmaf(a[5], d, b1.y);
    o1.z = fmaf(a[6], d, b1.z); o1.w = fmaf(a[7], d, b1.w);
    if (NT) {
        __builtin_nontemporal_store(o0, reinterpret_cast<vf4*>(dst));
        __builtin_nontemporal_store(o1, reinterpret_cast<vf4*>(dst) + 1);
    } else {
        reinterpret_cast<vf4*>(dst)[0] = o0;
        reinterpret_cast<vf4*>(dst)[1] = o1;
    }
}

extern "C" void kernel_launch(void* const* d_in, const int* in_sizes, int n_in,
                              void* d_out, int out_size, void* d_ws, size_t ws_size,
                              hipStream_t stream) {
    const float* x   = (const float*)d_in[0];
    const int*   ei  = (const int*)d_in[1];
    const float* W1  = (const float*)d_in[2];
    const float* b1  = (const float*)d_in[3];
    const float* Wmu = (const float*)d_in[4];
    const float* bmu = (const float*)d_in[5];
    const float* Wls = (const float*)d_in[6];
    const float* bls = (const float*)d_in[7];

    const int N = in_sizes[0] / 128;
    const int E = in_sizes[1] / 2;
    const int* row = ei;             // sources
    const int* col = ei + E;         // targets
    const int B = (N + NB - 1) >> SH;   // 128-node buckets (<= BMAX)
    const size_t BCAP = (size_t)B * CAP;
    const size_t PL = (size_t)16 * N;   // one bf16 [N][32] plane, in 4B units

    // ws layout (4B units), no overlays:
    // ccur[512] | binned[BCAP] | srcidx ushort[BCAP] (BCAP/2) |
    // t_lo[PL] | t_hi[PL] | t2_lo[PL] | t2_hi[PL] | dinv[N] | range2 int2[N]
    int* wsi = (int*)d_ws;
    size_t off = 0;
    int* ccur = wsi + off;                                 off += BMAX;
    unsigned* binned = (unsigned*)(wsi + off);             off += BCAP;
    unsigned short* srcidx = (unsigned short*)(wsi + off); off += BCAP / 2;
    unsigned short* t_lo = (unsigned short*)(wsi + off);   off += PL;
    unsigned short* t_hi = (unsigned short*)(wsi + off);   off += PL;
    unsigned short* t2_lo = (unsigned short*)(wsi + off);  off += PL;
    unsigned short* t2_hi = (unsigned short*)(wsi + off);  off += PL;
    float* dinv = (float*)(wsi + off);                     off += N;
    int2* range2 = (int2*)(wsi + off);                     off += 2 * (size_t)N;
    float* outp = (float*)d_out;

    const int GG = 2 * ((N * 4 + 255) / 256);   // both planes, parity-split
    const int NT64 = (N + 63) / 64;

    (void)hipMemsetAsync(ccur, 0, BMAX * sizeof(int), stream);
    k_bin<<<(E + CHUNK - 1) / CHUNK, 256, 0, stream>>>(row, col, ccur, binned, E, B);
    k_fine_gemm1<<<B, 256, 0, stream>>>(binned, ccur, srcidx, range2, dinv,
                                        x, W1, t_lo, t_hi, N);
    k_gatherB<<<NT64, 256, 0, stream>>>(
        range2, srcidx, (const uint4*)t_lo, (const uint4*)t_hi, dinv,
        b1, Wmu, Wls, t2_lo, t2_hi, N);
    k_gather<true><<<GG, 256, 0, stream>>>(
        range2, srcidx, (const uint4*)t2_lo, (const uint4*)t2_hi, dinv,
        bmu, bls, outp, outp + 32 * (size_t)N, N);
}

// Round 10
// 221.043 us; speedup vs baseline: 1.2044x; 1.2044x over previous
//
#include <hip/hip_runtime.h>
#include <hip/hip_bf16.h>

// GCN VGAE encoder, 6 dispatches (R5 structure, 512-thread fine_gemm1):
//   memset ccur | k_bin (LDS counting-sort, 8192-edge chunks) |
//   k_fine_gemm1 (512 threads/bucket: fine scan + srcidx emit + same-block gemm1) |
//   k_gather<L1, XCD-parity planes> | k_gemm2 | k_gather<L2 -> out>
// norm factorization: agg[c] = dinv[c]*(sum_e ts[src] + ts[c]) + b, ts = (X@W)*dinv.
// Journal: coop grid.sync ~75us (R11); gather+gemm fusion blows VGPRs to 244 even
// with sequential p-loop (R20/R21 REGRESSED; hipcc unrolls trip-2 loops; family
// dead). Degree-perm REGRESSED (R14). Scattered global atomics ~30ns/op (R15).
// R16: ~26.5us per gather dispatch incl ~11us dispatch overhead (3x-replication).
// R17: counting-sort k_bin + LDS-staged srcidx: 231.7->223.6 (srcidx stage = win).
// R18: gemm1 fused into k_fine: 43us kernel, 13% occ; 223.2 best (R5, passed 2x).
// R19: k_bin CHUNK 8192 ~= 2048 -> k_bin <43us; dispatch gaps ~10-17us dominate.
// R22 (SH=6): FAILED determinism tripwire -- fp32 gather order depends on
//   cross-block ccur claim order; 611K fine claims broke launch-vs-graph bit
//   reproducibility. KEEP CLAIMS COARSE (196x391). SH=6 dead.
// R23 (this): fine_gemm1 256->512 threads (same buckets/claims as R5): occupancy
//   ceiling 18.75->37.5%, phase-A serial work over 8 waves, gemm1 4 nodes/thread.

constexpr int SH = 7;            // nodes per coarse bucket = 128
constexpr int NB = 1 << SH;      // 128
constexpr int CAP = 6144;        // slab capacity (mean ~4093, ~32 sigma)
constexpr int BMAX = 512;        // max buckets (N <= 65536)
constexpr int CHUNK = 8192;      // edges per block in k_bin
constexpr int EPT = 12;          // register-cached edges/thread in k_fine (12*512=CAP)

typedef float vf4 __attribute__((ext_vector_type(4)));   // for nontemporal stores

__device__ __forceinline__ void fma4(float4& a, float s, const float4& w) {
    a.x = fmaf(s, w.x, a.x);
    a.y = fmaf(s, w.y, a.y);
    a.z = fmaf(s, w.z, a.z);
    a.w = fmaf(s, w.w, a.w);
}

__device__ __forceinline__ unsigned short f2bf(float f) {  // RNE
    unsigned u = __float_as_uint(f);
    return (unsigned short)((u + 0x7fffu + ((u >> 16) & 1u)) >> 16);
}

__device__ __forceinline__ void acc_bf8(float* a, uint4 v) {
    a[0] += __uint_as_float(v.x << 16);
    a[1] += __uint_as_float(v.x & 0xffff0000u);
    a[2] += __uint_as_float(v.y << 16);
    a[3] += __uint_as_float(v.y & 0xffff0000u);
    a[4] += __uint_as_float(v.z << 16);
    a[5] += __uint_as_float(v.z & 0xffff0000u);
    a[6] += __uint_as_float(v.w << 16);
    a[7] += __uint_as_float(v.w & 0xffff0000u);
}

__device__ __forceinline__ void set_bf8(float* a, uint4 v) {
    a[0] = __uint_as_float(v.x << 16);
    a[1] = __uint_as_float(v.x & 0xffff0000u);
    a[2] = __uint_as_float(v.y << 16);
    a[3] = __uint_as_float(v.y & 0xffff0000u);
    a[4] = __uint_as_float(v.z << 16);
    a[5] = __uint_as_float(v.z & 0xffff0000u);
    a[6] = __uint_as_float(v.w << 16);
    a[7] = __uint_as_float(v.w & 0xffff0000u);
}

// Sum of one (node, quad) stripe of a 32-feat bf16 plane into a[8] (fp32),
// including the self loop. 8-edge unroll for MLP.
__device__ __forceinline__ void gather_core(const int2* __restrict__ range2,
                                            const unsigned short* __restrict__ srcidx,
                                            const uint4* __restrict__ Tp,
                                            int n, int q, float* a) {
    int2 rg = range2[n];
    int k = rg.x, end = rg.y;
    set_bf8(a, Tp[(size_t)n * 4 + q]);       // self loop
    for (; k < end && (k & 3); ++k)          // align to ushort4
        acc_bf8(a, Tp[(size_t)srcidx[k] * 4 + q]);
    for (; k + 8 <= end; k += 8) {
        ushort4 r0 = *reinterpret_cast<const ushort4*>(srcidx + k);
        ushort4 r1 = *reinterpret_cast<const ushort4*>(srcidx + k + 4);
        uint4 v0 = Tp[(size_t)r0.x * 4 + q];
        uint4 v1 = Tp[(size_t)r0.y * 4 + q];
        uint4 v2 = Tp[(size_t)r0.z * 4 + q];
        uint4 v3 = Tp[(size_t)r0.w * 4 + q];
        uint4 v4 = Tp[(size_t)r1.x * 4 + q];
        uint4 v5 = Tp[(size_t)r1.y * 4 + q];
        uint4 v6 = Tp[(size_t)r1.z * 4 + q];
        uint4 v7 = Tp[(size_t)r1.w * 4 + q];
        acc_bf8(a, v0); acc_bf8(a, v1); acc_bf8(a, v2); acc_bf8(a, v3);
        acc_bf8(a, v4); acc_bf8(a, v5); acc_bf8(a, v6); acc_bf8(a, v7);
    }
    if (k + 4 <= end) {
        ushort4 r0 = *reinterpret_cast<const ushort4*>(srcidx + k);
        uint4 v0 = Tp[(size_t)r0.x * 4 + q];
        uint4 v1 = Tp[(size_t)r0.y * 4 + q];
        uint4 v2 = Tp[(size_t)r0.z * 4 + q];
        uint4 v3 = Tp[(size_t)r0.w * 4 + q];
        acc_bf8(a, v0); acc_bf8(a, v1); acc_bf8(a, v2); acc_bf8(a, v3);
        k += 4;
    }
    for (; k < end; ++k)
        acc_bf8(a, Tp[(size_t)srcidx[k] * 4 + q]);
}

// ---------------- k_bin ----------------
// LDS counting-sort per 8192-edge chunk:
//   pass1 hist(col>>SH) -> 512-wide block scan -> ONE ccur atomic per (block,bucket)
//   -> pass2 scatter packed edges into LDS sorted order -> contiguous run writes.
__global__ __launch_bounds__(256) void k_bin(const int* __restrict__ row,
                                             const int* __restrict__ col,
                                             int* __restrict__ ccur,
                                             unsigned* __restrict__ binned,
                                             int E, int B) {
    __shared__ int h[BMAX];       // hist -> running local offset
    __shared__ int lbase[BMAX];   // local exclusive base of bucket run
    __shared__ int gbase[BMAX];   // global slab base claimed for this block's run
    __shared__ int segtot[8];
    __shared__ unsigned sorted[CHUNK];   // 32KB
    const int tid = threadIdx.x;
    const int e0 = blockIdx.x * CHUNK;
    const int ecnt = min(E - e0, CHUNK);
    for (int i = tid; i < B; i += 256) h[i] = 0;
    __syncthreads();
    // pass1: histogram on col only
    for (int i = tid; i < ecnt; i += 256)
        atomicAdd(&h[col[e0 + i] >> SH], 1);
    __syncthreads();
    // block-wide exclusive scan over B (<=512) counts: 8 wave-segments + fixup
    int a0 = (tid < B) ? h[tid] : 0;
    int a1 = (tid + 256 < B) ? h[tid + 256] : 0;
    const int lane = tid & 63, wv = tid >> 6;
    int s0 = a0, s1 = a1;
    #pragma unroll
    for (int off = 1; off < 64; off <<= 1) {
        int u0 = __shfl_up(s0, off, 64);
        int u1 = __shfl_up(s1, off, 64);
        if (lane >= off) { s0 += u0; s1 += u1; }
    }
    if (lane == 63) { segtot[wv] = s0; segtot[4 + wv] = s1; }
    __syncthreads();
    int p0 = 0, p1 = 0;
    for (int j = 0; j < wv; ++j) p0 += segtot[j];
    for (int j = 0; j < 4 + wv; ++j) p1 += segtot[j];
    const int ex0 = s0 + p0 - a0;          // exclusive prefix, lanes [0,256)
    const int ex1 = s1 + p1 - a1;          // exclusive prefix, lanes [256,512)
    if (tid < B) {
        lbase[tid] = ex0; h[tid] = ex0;
        gbase[tid] = a0 ? atomicAdd(&ccur[tid], a0) : 0;
    }
    if (tid + 256 < B) {
        lbase[tid + 256] = ex1; h[tid + 256] = ex1;
        gbase[tid + 256] = a1 ? atomicAdd(&ccur[tid + 256], a1) : 0;
    }
    __syncthreads();
    // pass2: scatter into LDS sorted-by-bucket order (col reread: L2-hot)
    for (int i = tid; i < ecnt; i += 256) {
        int c = col[e0 + i], r = row[e0 + i];
        int pos = atomicAdd(&h[c >> SH], 1);
        sorted[pos] = ((unsigned)c << 16) | (unsigned)r;
    }
    __syncthreads();
    // write out: consecutive i within a run -> consecutive global addresses
    for (int i = tid; i < ecnt; i += 256) {
        unsigned e = sorted[i];
        int b = e >> (16 + SH);
        int g = gbase[b] + (i - lbase[b]);
        if (g < CAP) binned[(size_t)b * CAP + g] = e;
    }
}

// ---------------- k_fine_gemm1 (fused, 512 threads) ----------------
// One block per 128-node bucket, 8 waves:
//   phase A: register-cache entries (EPT=12, 12*512=CAP, no tails); fine histogram
//            -> dinv + ranges (two-wave scan over 128); srcidx via 12KB LDS stage
//            + coalesced burst.
//   phase B: gemm1 for THIS bucket's 128 nodes, 4 nodes/thread. W1 (32KB) staged
//            early so its latency hides under phase A. T = (X@W1)*dinv -> bf16.
__global__ __launch_bounds__(512) void k_fine_gemm1(
    const unsigned* __restrict__ binned, const int* __restrict__ ccur,
    unsigned short* __restrict__ srcidx, int2* __restrict__ range2,
    float* __restrict__ dinv,
    const float* __restrict__ X, const float* __restrict__ W1,
    unsigned short* __restrict__ Tlo, unsigned short* __restrict__ Thi, int N) {
    __shared__ int fine[NB];
    __shared__ float dl[NB];
    __shared__ int w0tot;
    __shared__ uint4 sshv[CAP / 8];               // 12KB ushort stage
    __shared__ float4 Wl[2048];                   // 32KB W1 tile
    unsigned short* ssh = (unsigned short*)sshv;
    const int b = blockIdx.x;
    const int n0 = b << SH;
    const int ebase = b * CAP;
    const int ecnt = min(ccur[b], CAP);
    const int tid = threadIdx.x;
    if (tid < NB) fine[tid] = 0;
    // ---- phase A: fine binning ----
    unsigned ebuf[EPT];
    #pragma unroll
    for (int j = 0; j < EPT; ++j) {
        int i = tid + j * 512;
        ebuf[j] = (i < ecnt) ? binned[ebase + i] : 0xFFFFFFFFu;
    }
    // stage W1 early: global loads issue now, latency retires under phase A
    for (int i = tid; i < 2048; i += 512)
        Wl[i] = reinterpret_cast<const float4*>(W1)[i];
    __syncthreads();
    #pragma unroll
    for (int j = 0; j < EPT; ++j)
        if (ebuf[j] != 0xFFFFFFFFu) atomicAdd(&fine[(ebuf[j] >> 16) & (NB - 1)], 1);
    __syncthreads();
    // exclusive scan over 128 counts: per-wave inclusive scan, wave1 += wave0 total
    int v = (tid < NB) ? fine[tid] : 0;
    int s = v;
    const int lane = tid & 63;
    #pragma unroll
    for (int off = 1; off < 64; off <<= 1) {
        int u = __shfl_up(s, off, 64);
        if (lane >= off) s += u;
    }
    if (tid == 63) w0tot = s;
    __syncthreads();
    if (tid >= 64 && tid < NB) s += w0tot;
    if (tid < NB) {
        int lb = s - v;                    // LOCAL exclusive base
        int n = n0 + tid;
        float d = rsqrtf((float)v + 1.0f);
        dl[tid] = d;
        if (n < N) {
            range2[n] = make_int2(ebase + lb, ebase + lb + v);
            dinv[n] = d;
        }
        fine[tid] = lb;                    // local running counter
    }
    __syncthreads();
    #pragma unroll
    for (int j = 0; j < EPT; ++j) {
        unsigned e = ebuf[j];
        if (e != 0xFFFFFFFFu) {
            int pos = atomicAdd(&fine[(e >> 16) & (NB - 1)], 1);
            ssh[pos] = (unsigned short)(e & 0xFFFFu);
        }
    }
    __syncthreads();
    // coalesced srcidx copy-out (round up to 16B; slack stays inside this slab)
    const int n4 = ((ecnt + 7) & ~7) >> 3;
    uint4* gs = reinterpret_cast<uint4*>(srcidx + ebase);
    for (int j = tid; j < n4; j += 512) gs[j] = sshv[j];

    // ---- phase B: gemm1 for nodes [n0, n0+128), 4 nodes/thread ----
    const int fg = tid & 15;           // 16 feature groups x float4 = 64 outputs
    const int ns = tid >> 4;           // 32 node slots
    const float4* Xv = reinterpret_cast<const float4*>(X);
    const float4 z = make_float4(0.f, 0.f, 0.f, 0.f);
    float4 acc[4] = {z, z, z, z};
    int n[4];
    bool vld[4];
    #pragma unroll
    for (int i = 0; i < 4; ++i) { n[i] = n0 + ns + i * 32; vld[i] = n[i] < N; }
    for (int k4 = 0; k4 < 32; ++k4) {
        float4 xv[4];
        #pragma unroll
        for (int i = 0; i < 4; ++i)
            xv[i] = vld[i] ? Xv[(size_t)n[i] * 32 + k4] : z;
        float4 w0 = Wl[(k4 * 4 + 0) * 16 + fg];
        float4 w1 = Wl[(k4 * 4 + 1) * 16 + fg];
        float4 w2 = Wl[(k4 * 4 + 2) * 16 + fg];
        float4 w3 = Wl[(k4 * 4 + 3) * 16 + fg];
        #pragma unroll
        for (int i = 0; i < 4; ++i) {
            fma4(acc[i], xv[i].x, w0); fma4(acc[i], xv[i].y, w1);
            fma4(acc[i], xv[i].z, w2); fma4(acc[i], xv[i].w, w3);
        }
    }
    ushort4* Tp = reinterpret_cast<ushort4*>((fg < 8) ? Tlo : Thi);
    const int j = fg & 7;
    #pragma unroll
    for (int i = 0; i < 4; ++i) {
        if (vld[i]) {
            float d = dl[ns + i * 32];
            ushort4 o;
            o.x = f2bf(acc[i].x * d); o.y = f2bf(acc[i].y * d);
            o.z = f2bf(acc[i].z * d); o.w = f2bf(acc[i].w * d);
            Tp[(size_t)n[i] * 8 + j] = o;
        }
    }
}

// ---------------- k_gemm ----------------
// T planes (bf16 [N][32] x2) = (op(X) @ W) * dinv[n]. 4 nodes/thread, 64-node tiles.
// PIN: X given as two fp32 [N][32] planes (layer 2); else contiguous [N][K].
template <int K, bool RELU, bool TWO_W, bool PIN>
__global__ __launch_bounds__(256) void k_gemm(const float* __restrict__ X,
                                              const float* __restrict__ Xhi,
                                              const float* __restrict__ Wa,
                                              const float* __restrict__ Wb,
                                              const float* __restrict__ dinv,
                                              unsigned short* __restrict__ Tlo,
                                              unsigned short* __restrict__ Thi, int N) {
    __shared__ float4 Wl[K * 16];
    const int tid = threadIdx.x;
    for (int i = tid; i < K * 16; i += 256) {
        if (TWO_W) {
            int k = i >> 4, fgi = i & 15;
            const float* s = (fgi < 8) ? (Wa + k * 32 + fgi * 4)
                                       : (Wb + k * 32 + (fgi - 8) * 4);
            Wl[i] = *reinterpret_cast<const float4*>(s);
        } else {
            Wl[i] = reinterpret_cast<const float4*>(Wa)[i];
        }
    }
    __syncthreads();

    const int fg = tid & 15;
    const int ns = tid >> 4;
    const int nb = blockIdx.x * 64;
    const float4* Xv = reinterpret_cast<const float4*>(X);
    const float4* Xv2 = reinterpret_cast<const float4*>(Xhi);
    const float4 z = make_float4(0.f, 0.f, 0.f, 0.f);
    float4 acc[4] = {z, z, z, z};
    int n[4];
    bool v[4];
    #pragma unroll
    for (int i = 0; i < 4; ++i) { n[i] = nb + ns + i * 16; v[i] = n[i] < N; }

    for (int k4 = 0; k4 < K / 4; ++k4) {
        float4 xv[4];
        #pragma unroll
        for (int i = 0; i < 4; ++i) {
            if (PIN)
                xv[i] = v[i] ? ((k4 < 8) ? Xv[(size_t)n[i] * 8 + k4]
                                         : Xv2[(size_t)n[i] * 8 + (k4 - 8)]) : z;
            else
                xv[i] = v[i] ? Xv[(size_t)n[i] * (K / 4) + k4] : z;
            if (RELU) {
                xv[i].x = fmaxf(xv[i].x, 0.f); xv[i].y = fmaxf(xv[i].y, 0.f);
                xv[i].z = fmaxf(xv[i].z, 0.f); xv[i].w = fmaxf(xv[i].w, 0.f);
            }
        }
        float4 w0 = Wl[(k4 * 4 + 0) * 16 + fg];
        float4 w1 = Wl[(k4 * 4 + 1) * 16 + fg];
        float4 w2 = Wl[(k4 * 4 + 2) * 16 + fg];
        float4 w3 = Wl[(k4 * 4 + 3) * 16 + fg];
        #pragma unroll
        for (int i = 0; i < 4; ++i) {
            fma4(acc[i], xv[i].x, w0); fma4(acc[i], xv[i].y, w1);
            fma4(acc[i], xv[i].z, w2); fma4(acc[i], xv[i].w, w3);
        }
    }
    ushort4* Tp = reinterpret_cast<ushort4*>((fg < 8) ? Tlo : Thi);
    const int j = fg & 7;
    #pragma unroll
    for (int i = 0; i < 4; ++i) {
        if (v[i]) {
            float d = dinv[n[i]];
            ushort4 o;
            o.x = f2bf(acc[i].x * d); o.y = f2bf(acc[i].y * d);
            o.z = f2bf(acc[i].z * d); o.w = f2bf(acc[i].w * d);
            Tp[(size_t)n[i] * 8 + j] = o;
        }
    }
}

// ---------------- k_gather ----------------
// Both planes of one layer in a single dispatch, plane pinned by XCD parity:
// plane = blockIdx&1 (round-robin block->XCD mapping keeps each XCD on one 3.2MB
// plane -> per-XCD L2-resident). Grid = 2 * ceil(N*4/256).
template <bool NT>
__global__ __launch_bounds__(256) void k_gather(
    const int2* __restrict__ range2, const unsigned short* __restrict__ srcidx,
    const uint4* __restrict__ Tlo, const uint4* __restrict__ Thi,
    const float* __restrict__ dinv,
    const float* __restrict__ bias_lo, const float* __restrict__ bias_hi,
    float* __restrict__ dst_lo, float* __restrict__ dst_hi, int N) {
    const int plane = blockIdx.x & 1;
    int idx = (blockIdx.x >> 1) * 256 + threadIdx.x;
    if (idx >= N * 4) return;
    int n = idx >> 2, q = idx & 3;
    float a[8];
    gather_core(range2, srcidx, plane ? Thi : Tlo, n, q, a);
    float d = dinv[n];
    const float* bias = (plane ? bias_hi : bias_lo) + q * 8;
    float* dst = (plane ? dst_hi : dst_lo) + (size_t)n * 32 + q * 8;
    float4 b0 = reinterpret_cast<const float4*>(bias)[0];
    float4 b1 = reinterpret_cast<const float4*>(bias)[1];
    vf4 o0, o1;
    o0.x = fmaf(a[0], d, b0.x); o0.y = fmaf(a[1], d, b0.y);
    o0.z = fmaf(a[2], d, b0.z); o0.w = fmaf(a[3], d, b0.w);
    o1.x = fmaf(a[4], d, b1.x); o1.y = fmaf(a[5], d, b1.y);
    o1.z = fmaf(a[6], d, b1.z); o1.w = fmaf(a[7], d, b1.w);
    if (NT) {
        __builtin_nontemporal_store(o0, reinterpret_cast<vf4*>(dst));
        __builtin_nontemporal_store(o1, reinterpret_cast<vf4*>(dst) + 1);
    } else {
        reinterpret_cast<vf4*>(dst)[0] = o0;
        reinterpret_cast<vf4*>(dst)[1] = o1;
    }
}

extern "C" void kernel_launch(void* const* d_in, const int* in_sizes, int n_in,
                              void* d_out, int out_size, void* d_ws, size_t ws_size,
                              hipStream_t stream) {
    const float* x   = (const float*)d_in[0];
    const int*   ei  = (const int*)d_in[1];
    const float* W1  = (const float*)d_in[2];
    const float* b1  = (const float*)d_in[3];
    const float* Wmu = (const float*)d_in[4];
    const float* bmu = (const float*)d_in[5];
    const float* Wls = (const float*)d_in[6];
    const float* bls = (const float*)d_in[7];

    const int N = in_sizes[0] / 128;
    const int E = in_sizes[1] / 2;
    const int* row = ei;             // sources
    const int* col = ei + E;         // targets
    const int B = (N + NB - 1) >> SH;   // 128-node buckets (<= BMAX)
    const size_t BCAP = (size_t)B * CAP;
    const size_t PL = (size_t)16 * N;   // one bf16 [N][32] plane, in 4B units

    // ws layout (4B units), no overlays:
    // ccur[512] | binned[BCAP] | srcidx ushort[BCAP] (BCAP/2) |
    // t_lo[PL] | t_hi[PL] | dinv[N] | range2 int2[N] | agg_lo f32[32N] | agg_hi f32[32N]
    int* wsi = (int*)d_ws;
    size_t off = 0;
    int* ccur = wsi + off;                                 off += BMAX;
    unsigned* binned = (unsigned*)(wsi + off);             off += BCAP;
    unsigned short* srcidx = (unsigned short*)(wsi + off); off += BCAP / 2;
    unsigned short* t_lo = (unsigned short*)(wsi + off);   off += PL;
    unsigned short* t_hi = (unsigned short*)(wsi + off);   off += PL;
    float* dinv = (float*)(wsi + off);                     off += N;
    int2* range2 = (int2*)(wsi + off);                     off += 2 * (size_t)N;
    float* agg_lo = (float*)(wsi + off);                   off += 32 * (size_t)N;
    float* agg_hi = (float*)(wsi + off);                   off += 32 * (size_t)N;
    float* outp = (float*)d_out;

    const int GG = 2 * ((N * 4 + 255) / 256);   // both planes, parity-split
    const int ntiles = (N + 63) / 64;

    (void)hipMemsetAsync(ccur, 0, BMAX * sizeof(int), stream);
    k_bin<<<(E + CHUNK - 1) / CHUNK, 256, 0, stream>>>(row, col, ccur, binned, E, B);
    k_fine_gemm1<<<B, 512, 0, stream>>>(binned, ccur, srcidx, range2, dinv,
                                        x, W1, t_lo, t_hi, N);
    k_gather<false><<<GG, 256, 0, stream>>>(
        range2, srcidx, (const uint4*)t_lo, (const uint4*)t_hi, dinv,
        b1, b1 + 32, agg_lo, agg_hi, N);

    k_gemm<64, true, true, true><<<ntiles, 256, 0, stream>>>(
        agg_lo, agg_hi, Wmu, Wls, dinv, t_lo, t_hi, N);
    k_gather<true><<<GG, 256, 0, stream>>>(
        range2, srcidx, (const uint4*)t_lo, (const uint4*)t_hi, dinv,
        bmu, bls, outp, outp + 32 * (size_t)N, N);
}